// Round 15
// baseline (579.560 us; speedup 1.0000x reference)
//
#include <hip/hip_runtime.h>
#include <math.h>

// Matrix-Tree marginals: probs[b,i,j] = A[i,j]*(X[i-1,i-1] - (j>=1 ? X[j-1,i-1] : 0))
// X = inv(M) via blocked in-place Gauss-Jordan (4 panel steps of 64, SDD -> no pivoting).
// Round-15: R13 (549us validated) + MFMA phase 3 with SELF-CALIBRATING layout probes.
// R14's MFMA failed (absmax 0.19) with no identifiable race; the unverified premise was the
// f64 MFMA fragment layout on gfx950 (guide verified every dtype EXCEPT f64). Two probe
// MFMAs decode the true D row/col lane-mapping at runtime (robust to any per-lane
// permutation of A-rows/B-cols/D-rows/D-cols + any consistent k-map); phase 3 indexes
// through the decoded tables. Phases 1-2 and all other kernels byte-identical to R13.
// ws (doubles): M[B][256][256] | mb[B] | nb[B](int) | Dg[B][256]; partial aliases Dg.

#define S 256
#define BB 256

typedef double f64x4 __attribute__((ext_vector_type(4)));

__device__ __forceinline__ int rowmap(int lr, int kb) {   // local 0..191 -> global row skipping panel kb
    int rt = lr >> 6;
    int rb = rt + (rt >= kb ? 1 : 0);
    return rb * 64 + (lr & 63);
}

// ---------------- kernel 1a: dense max over each batch's full 256x256 score matrix ----------
__global__ __launch_bounds__(256) void k_max(const float* __restrict__ sc,
                                             float* __restrict__ partial) {
    int b = blockIdx.y, rg = blockIdx.x;                 // 8 row-groups of 32 rows
    const float4* p4 = (const float4*)(sc + (size_t)b * S * S + rg * 8192);
    int tid = threadIdx.x;
    float4 v[8];
    #pragma unroll
    for (int it = 0; it < 8; ++it) v[it] = p4[tid + 256 * it];
    float m = -1e30f;
    #pragma unroll
    for (int it = 0; it < 8; ++it)
        m = fmaxf(m, fmaxf(fmaxf(v[it].x, v[it].y), fmaxf(v[it].z, v[it].w)));
    for (int off = 32; off > 0; off >>= 1) m = fmaxf(m, __shfl_down(m, off));
    __shared__ float sm[4];
    if ((tid & 63) == 0) sm[tid >> 6] = m;
    __syncthreads();
    if (tid == 0) partial[b * 8 + rg] = fmaxf(fmaxf(sm[0], sm[1]), fmaxf(sm[2], sm[3]));
}

// ---------------- kernel 1b: per-batch n (mask count) + combine partial maxima --------------
__global__ void k_n(const unsigned char* __restrict__ mk, const float* __restrict__ partial,
                    double* __restrict__ mb, int* __restrict__ nb) {
    int b = blockIdx.x, j = threadIdx.x;
    __shared__ int shc[4];

    const unsigned int* mw = (const unsigned int*)mk;    // sniff mask dtype
    unsigned int w0 = mw[0], w1 = mw[1];
    int mode = (w0 != 0u) ? 0 : ((w1 != 0u) ? 1 : 2);

    int c;
    if (mode == 0)      c = (mk[(size_t)b * S + j] != 0);
    else if (mode == 1) c = (((const int*)mk)[(size_t)b * S + j] != 0);
    else                c = (((const long long*)mk)[(size_t)b * S + j] != 0LL);

    int lane = j & 63, wid = j >> 6;
    int cs = c;
    for (int off = 32; off > 0; off >>= 1) cs += __shfl_down(cs, off);
    if (lane == 0) shc[wid] = cs;
    __syncthreads();
    if (j == 0) {
        nb[b] = shc[0] + shc[1] + shc[2] + shc[3];
        float mm = partial[b * 8];
        #pragma unroll
        for (int q = 1; q < 8; ++q) mm = fmaxf(mm, partial[b * 8 + q]);
        mb[b] = (double)mm;
    }
}

// ---------------- kernel 2: build padded M (f64, expf), 4 rows per block --------------------
__global__ __launch_bounds__(256) void k_build(const float* __restrict__ sc,
                                               const double* __restrict__ mb,
                                               const int* __restrict__ nb,
                                               double* __restrict__ Mg) {
    int b = blockIdx.y;
    int wid = threadIdx.x >> 6, lane = threadIdx.x & 63;
    int p = blockIdx.x * 4 + wid;
    int n = nb[b];
    double m = mb[b];
    __shared__ double se[4][260];
    double* Mrow = Mg + ((size_t)b * S + p) * S;
    bool act = (p < n);
    double ssum = 0.0;
    #pragma unroll
    for (int c4 = 0; c4 < 4; ++c4) {
        int j = lane + 64 * c4;
        double ev = 0.0;
        if (act && j <= n)
            ev = (double)expf((float)((double)sc[((size_t)b * S + (p + 1)) * S + j] - m));
        se[wid][j] = ev;
        ssum += ev;
    }
    for (int off = 32; off > 0; off >>= 1) ssum += __shfl_down(ssum, off);
    ssum = __shfl(ssum, 0);
    __syncthreads();                       // uniform: all 4 waves reach it
    #pragma unroll
    for (int c4 = 0; c4 < 4; ++c4) {
        int j = lane + 64 * c4;
        double v;
        if (act && j < n) v = ((j == p) ? ssum : 0.0) - se[wid][j + 1];
        else              v = (j == p) ? 1.0 : 0.0;
        Mrow[j] = v;
    }
}

// ---------------- kernel 3: fused panel step (GJ + rowG + probe-calibrated MFMA update) -----
__global__ __launch_bounds__(512) void k_step(double* __restrict__ Mg, int kb) {
    int b = blockIdx.x;
    double* M = Mg + (size_t)b * S * S;
    int tid = threadIdx.x;
    __shared__ double H[64 * 256];     // [G | Pinv] by GLOBAL column index, rows = pivot rows
    __shared__ double SCR[3104];       // union: GJ bufs (256) | PT(512)+Rc(1536)
    __shared__ int rowtab[16];         // decoded D-row map: rowtab[(lane>>4)*4 + v]

    // ---- MFMA layout probes (decode true D row/col lane-maps at runtime) ----
    int pl = tid & 63;
    int pli = pl & 15, plk = pl >> 4;
    {
        f64x4 pr = {0.0, 0.0, 0.0, 0.0}, pc = {0.0, 0.0, 0.0, 0.0};
        // probe R: A[:,k0] = row-id+1, B = e00  =>  D[i][j0] = i+1, else 0
        pr = __builtin_amdgcn_mfma_f64_16x16x4f64((plk == 0) ? (double)(pli + 1) : 0.0,
                                                  (plk == 0 && pli == 0) ? 1.0 : 0.0,
                                                  pr, 0, 0, 0);
        // probe C: A[:,k0] = 1, B[k0,:] = col-id+1  =>  D[i][j] = col(j)+1
        pc = __builtin_amdgcn_mfma_f64_16x16x4f64((plk == 0) ? 1.0 : 0.0,
                                                  (plk == 0) ? (double)(pli + 1) : 0.0,
                                                  pc, 0, 0, 0);
        int cof = (int)pc[0] - 1;      // this lane's true output-column offset (0..15)
        if (cof == 0) {                // this lane reads column j0: pr[v] = true-row+1
            #pragma unroll
            for (int v = 0; v < 4; ++v) rowtab[plk * 4 + v] = (int)pr[v] - 1;
        }
        // fence before use: first GJ __syncthreads below
    }

    // ---- phase 1: register GJ on the 64x64 diag block ----
    int i = tid >> 3, g = tid & 7, c0 = g << 3;   // row i, col group g (8 cols)
    double c[8];
    {
        const double* src = M + (size_t)(kb * 64 + i) * S + kb * 64 + c0;
        #pragma unroll
        for (int m2 = 0; m2 < 4; ++m2) {
            double2 t = *(const double2*)(src + 2 * m2);
            c[2 * m2] = t.x; c[2 * m2 + 1] = t.y;
        }
    }
    double* rbuf = SCR;          // [2][64]
    double* cbuf = SCR + 128;    // [2][64]
    if (i == 0) {
        #pragma unroll
        for (int u = 0; u < 8; ++u) rbuf[c0 + u] = c[u];
    }
    if (g == 0) cbuf[i] = c[0];
    for (int k = 0; k < 64; ++k) {
        int par = k & 1;
        __syncthreads();
        double pv = rbuf[par * 64 + k];
        double f  = cbuf[par * 64 + i];
        double rk[8];
        #pragma unroll
        for (int m2 = 0; m2 < 4; ++m2) {
            double2 t = *(const double2*)&rbuf[par * 64 + c0 + 2 * m2];
            rk[2 * m2] = t.x; rk[2 * m2 + 1] = t.y;
        }
        double pivinv = 1.0 / pv;
        int kg = k >> 3, ks = k & 7;
        if (i == k) {
            #pragma unroll
            for (int u = 0; u < 8; ++u)
                c[u] = ((g == kg) && (u == ks)) ? pivinv : c[u] * pivinv;
        } else {
            double gm = f * pivinv;
            #pragma unroll
            for (int u = 0; u < 8; ++u)
                c[u] = ((g == kg) && (u == ks)) ? (-gm) : fma(-gm, rk[u], c[u]);
        }
        int k1 = k + 1;
        if (k1 < 64) {
            if (i == k1) {
                #pragma unroll
                for (int u = 0; u < 8; ++u) rbuf[(par ^ 1) * 64 + c0 + u] = c[u];
            }
            if (g == (k1 >> 3)) cbuf[(par ^ 1) * 64 + i] = c[k1 & 7];
        }
    }
    __syncthreads();   // GJ done; SCR reusable. Threads hold Pinv[i][c0..c0+7] in c[].

    // ---- phase 2: G = Pinv * R_old  (8 chunks of 8 k-rows), G+Pinv -> H ----
    int tx = tid & 31, ty = tid >> 5;    // ty 0..15
    double* PT = SCR;                    // PT[sL][t] = Pinv[t][cs*8+sL]   [8][64]
    double* Rc = SCR + 512;              // Rc[sL][j] = R_old[cs*8+sL][j]  [8][192]
    double2 ga[4][3];
    #pragma unroll
    for (int r = 0; r < 4; ++r)
        #pragma unroll
        for (int q = 0; q < 3; ++q) ga[r][q] = double2{0.0, 0.0};

    for (int cs = 0; cs < 8; ++cs) {
        if (g == cs) {
            #pragma unroll
            for (int u = 0; u < 8; ++u) PT[u * 64 + i] = c[u];
        }
        #pragma unroll
        for (int rep = 0; rep < 3; ++rep) {
            int idx = rep * 512 + tid;
            int sL = idx / 192, jj = idx - sL * 192;
            Rc[sL * 192 + jj] = M[(size_t)(kb * 64 + cs * 8 + sL) * S + rowmap(jj, kb)];
        }
        __syncthreads();
        #pragma unroll
        for (int sL = 0; sL < 8; ++sL) {
            double2 p01 = *(const double2*)&PT[sL * 64 + 4 * ty];
            double2 p23 = *(const double2*)&PT[sL * 64 + 4 * ty + 2];
            double2 r0 = *(const double2*)&Rc[sL * 192 + 2 * tx];
            double2 r1 = *(const double2*)&Rc[sL * 192 + 2 * tx + 64];
            double2 r2 = *(const double2*)&Rc[sL * 192 + 2 * tx + 128];
            ga[0][0].x = fma(p01.x, r0.x, ga[0][0].x); ga[0][0].y = fma(p01.x, r0.y, ga[0][0].y);
            ga[0][1].x = fma(p01.x, r1.x, ga[0][1].x); ga[0][1].y = fma(p01.x, r1.y, ga[0][1].y);
            ga[0][2].x = fma(p01.x, r2.x, ga[0][2].x); ga[0][2].y = fma(p01.x, r2.y, ga[0][2].y);
            ga[1][0].x = fma(p01.y, r0.x, ga[1][0].x); ga[1][0].y = fma(p01.y, r0.y, ga[1][0].y);
            ga[1][1].x = fma(p01.y, r1.x, ga[1][1].x); ga[1][1].y = fma(p01.y, r1.y, ga[1][1].y);
            ga[1][2].x = fma(p01.y, r2.x, ga[1][2].x); ga[1][2].y = fma(p01.y, r2.y, ga[1][2].y);
            ga[2][0].x = fma(p23.x, r0.x, ga[2][0].x); ga[2][0].y = fma(p23.x, r0.y, ga[2][0].y);
            ga[2][1].x = fma(p23.x, r1.x, ga[2][1].x); ga[2][1].y = fma(p23.x, r1.y, ga[2][1].y);
            ga[2][2].x = fma(p23.x, r2.x, ga[2][2].x); ga[2][2].y = fma(p23.x, r2.y, ga[2][2].y);
            ga[3][0].x = fma(p23.y, r0.x, ga[3][0].x); ga[3][0].y = fma(p23.y, r0.y, ga[3][0].y);
            ga[3][1].x = fma(p23.y, r1.x, ga[3][1].x); ga[3][1].y = fma(p23.y, r1.y, ga[3][1].y);
            ga[3][2].x = fma(p23.y, r2.x, ga[3][2].x); ga[3][2].y = fma(p23.y, r2.y, ga[3][2].y);
        }
        __syncthreads();                 // inner reads done before next chunk restages SCR
    }
    // G -> H (global-column indexing), Pinv -> H pivot cols
    #pragma unroll
    for (int r = 0; r < 4; ++r)
        #pragma unroll
        for (int q = 0; q < 3; ++q) {
            int col = rowmap(2 * tx + 64 * q, kb);
            *(double2*)&H[(4 * ty + r) * 256 + col] = ga[r][q];
        }
    #pragma unroll
    for (int u = 0; u < 8; ++u) H[i * 256 + kb * 64 + c0 + u] = c[u];
    __syncthreads();                     // H complete

    // H -> M pivot rows (early: global writes drain under the update phase)
    #pragma unroll
    for (int rep = 0; rep < 16; ++rep) {
        int idx = rep * 512 + tid;
        int row = idx >> 7, col2 = idx & 127;
        *(double2*)&M[(size_t)(kb * 64 + row) * S + 2 * col2] =
            *(const double2*)&H[row * 256 + 2 * col2];
    }

    // ---- phase 3 (probe-calibrated MFMA): M[np rows] += (-F)*H ; pivot cols = (-F)*Pinv ----
    {
        int wv = tid >> 6;
        int li = pli, lk = plk;
        int ct0 = 2 * wv, ct1 = 2 * wv + 1;          // this wave's two col-tiles
        bool pivw = ((wv >> 1) == kb);               // wave owns the pivot col-tiles
        // decoded output coordinates for this lane
        f64x4 pc2 = {0.0, 0.0, 0.0, 0.0};
        pc2 = __builtin_amdgcn_mfma_f64_16x16x4f64((lk == 0) ? 1.0 : 0.0,
                                                   (lk == 0) ? (double)(li + 1) : 0.0,
                                                   pc2, 0, 0, 0);
        int cof = (int)pc2[0] - 1;
        int r0 = rowtab[lk * 4 + 0], r1 = rowtab[lk * 4 + 1];
        int r2 = rowtab[lk * 4 + 2], r3 = rowtab[lk * 4 + 3];
        for (int rt = 0; rt < 12; ++rt) {
            const double* Fp = M + (size_t)rowmap(rt * 16 + li, kb) * S + kb * 64 + lk;
            f64x4 acc0 = {0.0, 0.0, 0.0, 0.0};
            f64x4 acc1 = {0.0, 0.0, 0.0, 0.0};
            #pragma unroll
            for (int s = 0; s < 16; ++s) {
                double a  = -Fp[4 * s];                            // A = -F (global, L2-hot)
                double b0 = H[(4 * s + lk) * 256 + 16 * ct0 + li]; // B = H (LDS)
                double b1 = H[(4 * s + lk) * 256 + 16 * ct1 + li];
                acc0 = __builtin_amdgcn_mfma_f64_16x16x4f64(a, b0, acc0, 0, 0, 0);
                acc1 = __builtin_amdgcn_mfma_f64_16x16x4f64(a, b1, acc1, 0, 0, 0);
            }
            size_t g0 = (size_t)rowmap(rt * 16 + r0, kb) * S;
            size_t g1 = (size_t)rowmap(rt * 16 + r1, kb) * S;
            size_t g2 = (size_t)rowmap(rt * 16 + r2, kb) * S;
            size_t g3 = (size_t)rowmap(rt * 16 + r3, kb) * S;
            if (!pivw) {                              // non-pivot cols: RMW (no F alias)
                M[g0 + 16 * ct0 + cof] += acc0[0]; M[g0 + 16 * ct1 + cof] += acc1[0];
                M[g1 + 16 * ct0 + cof] += acc0[1]; M[g1 + 16 * ct1 + cof] += acc1[1];
                M[g2 + 16 * ct0 + cof] += acc0[2]; M[g2 + 16 * ct1 + cof] += acc1[2];
                M[g3 + 16 * ct0 + cof] += acc0[3]; M[g3 + 16 * ct1 + cof] += acc1[3];
            }
            __syncthreads();                          // all F-reads of this rt complete
            if (pivw) {                               // pivot cols overwrite F: after barrier
                M[g0 + 16 * ct0 + cof] = acc0[0]; M[g0 + 16 * ct1 + cof] = acc1[0];
                M[g1 + 16 * ct0 + cof] = acc0[1]; M[g1 + 16 * ct1 + cof] = acc1[1];
                M[g2 + 16 * ct0 + cof] = acc0[2]; M[g2 + 16 * ct1 + cof] = acc1[2];
                M[g3 + 16 * ct0 + cof] = acc0[3]; M[g3 + 16 * ct1 + cof] = acc1[3];
            }
        }
    }
}

// ---------------- kernel 4a: diag extract + row-0/col-0 epilogue ----------------------------
__global__ __launch_bounds__(256) void k_diag(const double* __restrict__ Mg,
                                              const float* __restrict__ sc,
                                              const double* __restrict__ mb,
                                              const int* __restrict__ nb,
                                              double* __restrict__ Dg,
                                              float* __restrict__ out) {
    int b = blockIdx.x, t = threadIdx.x;
    const double* M = Mg + (size_t)b * S * S;
    __shared__ double sd[256];
    double d = M[(size_t)t * S + t];
    sd[t] = d;
    Dg[(size_t)b * S + t] = d;
    out[(size_t)b * S * S + t] = 0.0f;            // row 0
    __syncthreads();
    int n = nb[b];
    float m = (float)mb[b];
    if (t >= 1) {                                 // col 0, rows 1..255
        float v = 0.0f;
        if (t <= n) {
            double A = (double)expf(sc[((size_t)b * S + t) * S + 0] - m);
            v = (float)(A * sd[t - 1]);
        }
        out[((size_t)b * S + t) * S + 0] = v;
    }
}

// ---------------- kernel 4b: fused transpose + epilogue (i,j >= 1) --------------------------
__global__ __launch_bounds__(256) void k_xtepi(const double* __restrict__ Mg,
                                               const float* __restrict__ sc,
                                               const double* __restrict__ mb,
                                               const int* __restrict__ nb,
                                               const double* __restrict__ Dg,
                                               float* __restrict__ out) {
    int b = blockIdx.y, t = blockIdx.x;
    int r = t & 3, c = t >> 2;
    const double* M = Mg + (size_t)b * S * S;
    __shared__ float L[64][65];
    __shared__ double sdg[64];
    int tid = threadIdx.x;
    int cc = tid & 63;
    #pragma unroll
    for (int rep = 0; rep < 16; ++rep) {
        int rr = rep * 4 + (tid >> 6);
        L[rr][cc] = (float)M[(size_t)(64 * r + rr) * S + 64 * c + cc];
    }
    if (tid < 64) sdg[tid] = Dg[(size_t)b * S + 64 * c + tid];
    __syncthreads();
    int n = nb[b];
    float m = (float)mb[b];
    int pp = tid & 63;
    #pragma unroll
    for (int rep = 0; rep < 16; ++rep) {
        int qq = rep * 4 + (tid >> 6);
        int orow = 64 * c + qq + 1, ocol = 64 * r + pp + 1;
        if (orow < 256 && ocol < 256) {
            float v = 0.0f;
            if (orow <= n && ocol <= n) {
                double A = (double)expf(sc[((size_t)b * S + orow) * S + ocol] - m);
                v = (float)(A * (sdg[qq] - (double)L[pp][qq]));
            }
            out[((size_t)b * S + orow) * S + ocol] = v;
        }
    }
}

// ---------------- launcher ----------------
extern "C" void kernel_launch(void* const* d_in, const int* in_sizes, int n_in,
                              void* d_out, int out_size, void* d_ws, size_t ws_size,
                              hipStream_t stream) {
    (void)in_sizes; (void)n_in; (void)out_size; (void)ws_size;
    const float* sc = (const float*)d_in[0];
    const unsigned char* mk = (const unsigned char*)d_in[1];
    double* ws = (double*)d_ws;

    double* M  = ws;                                 // B*256*256
    double* mb = M + (size_t)BB * S * S;             // B doubles
    int*    nb = (int*)(mb + BB);                    // B ints
    double* Dg = mb + 2 * BB;                        // B*256 doubles
    float*  partial = (float*)Dg;                    // aliases Dg (consumed before Dg written)
    float*  out = (float*)d_out;

    k_max<<<dim3(8, BB), 256, 0, stream>>>(sc, partial);
    k_n<<<BB, 256, 0, stream>>>(mk, partial, mb, nb);
    k_build<<<dim3(64, BB), 256, 0, stream>>>(sc, mb, nb, M);
    for (int kb = 0; kb < 4; ++kb)
        k_step<<<BB, 512, 0, stream>>>(M, kb);
    k_diag<<<BB, 256, 0, stream>>>(M, sc, mb, nb, Dg, out);
    k_xtepi<<<dim3(16, BB), 256, 0, stream>>>(M, sc, mb, nb, Dg, out);
}

// Round 16
// 552.969 us; speedup vs baseline: 1.0481x; 1.0481x over previous
//
#include <hip/hip_runtime.h>
#include <math.h>

// Matrix-Tree marginals: probs[b,i,j] = A[i,j]*(X[i-1,i-1] - (j>=1 ? X[j-1,i-1] : 0))
// X = inv(M) via blocked in-place Gauss-Jordan (4 panel steps of 64, SDD -> no pivoting).
// Round-16: R15 (probe-calibrated f64 MFMA phase 3, validated) + phase 2 ALSO on MFMA:
// G = Pinv*R with A = Pinv from H (A-map i=lane&15,k=lane>>4 validated by R15's pass),
// B = R straight from global M pivot rows, D -> H via decoded rowtab/cof. Removes phase-2's
// 16 barriers + LDS-pipe staging loop. H row stride 256->258 (A-reads were 16-way bank
// conflicts at 256; 258 -> 2-way, free). SCR shrinks to GJ bufs only.
// ws (doubles): M[B][256][256] | mb[B] | nb[B](int) | Dg[B][256]; partial aliases Dg.

#define S 256
#define BB 256
#define HS 258

typedef double f64x4 __attribute__((ext_vector_type(4)));

__device__ __forceinline__ int rowmap(int lr, int kb) {   // local 0..191 -> global row skipping panel kb
    int rt = lr >> 6;
    int rb = rt + (rt >= kb ? 1 : 0);
    return rb * 64 + (lr & 63);
}

// ---------------- kernel 1a: dense max over each batch's full 256x256 score matrix ----------
__global__ __launch_bounds__(256) void k_max(const float* __restrict__ sc,
                                             float* __restrict__ partial) {
    int b = blockIdx.y, rg = blockIdx.x;                 // 8 row-groups of 32 rows
    const float4* p4 = (const float4*)(sc + (size_t)b * S * S + rg * 8192);
    int tid = threadIdx.x;
    float4 v[8];
    #pragma unroll
    for (int it = 0; it < 8; ++it) v[it] = p4[tid + 256 * it];
    float m = -1e30f;
    #pragma unroll
    for (int it = 0; it < 8; ++it)
        m = fmaxf(m, fmaxf(fmaxf(v[it].x, v[it].y), fmaxf(v[it].z, v[it].w)));
    for (int off = 32; off > 0; off >>= 1) m = fmaxf(m, __shfl_down(m, off));
    __shared__ float sm[4];
    if ((tid & 63) == 0) sm[tid >> 6] = m;
    __syncthreads();
    if (tid == 0) partial[b * 8 + rg] = fmaxf(fmaxf(sm[0], sm[1]), fmaxf(sm[2], sm[3]));
}

// ---------------- kernel 1b: per-batch n (mask count) + combine partial maxima --------------
__global__ void k_n(const unsigned char* __restrict__ mk, const float* __restrict__ partial,
                    double* __restrict__ mb, int* __restrict__ nb) {
    int b = blockIdx.x, j = threadIdx.x;
    __shared__ int shc[4];

    const unsigned int* mw = (const unsigned int*)mk;    // sniff mask dtype
    unsigned int w0 = mw[0], w1 = mw[1];
    int mode = (w0 != 0u) ? 0 : ((w1 != 0u) ? 1 : 2);

    int c;
    if (mode == 0)      c = (mk[(size_t)b * S + j] != 0);
    else if (mode == 1) c = (((const int*)mk)[(size_t)b * S + j] != 0);
    else                c = (((const long long*)mk)[(size_t)b * S + j] != 0LL);

    int lane = j & 63, wid = j >> 6;
    int cs = c;
    for (int off = 32; off > 0; off >>= 1) cs += __shfl_down(cs, off);
    if (lane == 0) shc[wid] = cs;
    __syncthreads();
    if (j == 0) {
        nb[b] = shc[0] + shc[1] + shc[2] + shc[3];
        float mm = partial[b * 8];
        #pragma unroll
        for (int q = 1; q < 8; ++q) mm = fmaxf(mm, partial[b * 8 + q]);
        mb[b] = (double)mm;
    }
}

// ---------------- kernel 2: build padded M (f64, expf), 4 rows per block --------------------
__global__ __launch_bounds__(256) void k_build(const float* __restrict__ sc,
                                               const double* __restrict__ mb,
                                               const int* __restrict__ nb,
                                               double* __restrict__ Mg) {
    int b = blockIdx.y;
    int wid = threadIdx.x >> 6, lane = threadIdx.x & 63;
    int p = blockIdx.x * 4 + wid;
    int n = nb[b];
    double m = mb[b];
    __shared__ double se[4][260];
    double* Mrow = Mg + ((size_t)b * S + p) * S;
    bool act = (p < n);
    double ssum = 0.0;
    #pragma unroll
    for (int c4 = 0; c4 < 4; ++c4) {
        int j = lane + 64 * c4;
        double ev = 0.0;
        if (act && j <= n)
            ev = (double)expf((float)((double)sc[((size_t)b * S + (p + 1)) * S + j] - m));
        se[wid][j] = ev;
        ssum += ev;
    }
    for (int off = 32; off > 0; off >>= 1) ssum += __shfl_down(ssum, off);
    ssum = __shfl(ssum, 0);
    __syncthreads();                       // uniform: all 4 waves reach it
    #pragma unroll
    for (int c4 = 0; c4 < 4; ++c4) {
        int j = lane + 64 * c4;
        double v;
        if (act && j < n) v = ((j == p) ? ssum : 0.0) - se[wid][j + 1];
        else              v = (j == p) ? 1.0 : 0.0;
        Mrow[j] = v;
    }
}

// ---------------- kernel 3: fused panel step (GJ + MFMA rowG + MFMA update) -----------------
__global__ __launch_bounds__(512) void k_step(double* __restrict__ Mg, int kb) {
    int b = blockIdx.x;
    double* M = Mg + (size_t)b * S * S;
    int tid = threadIdx.x;
    __shared__ double H[64 * HS];      // [G | Pinv] by GLOBAL column index, rows = pivot rows
    __shared__ double SCR[256];        // GJ row/col broadcast buffers
    __shared__ int rowtab[16];         // decoded D-row map: rowtab[(lane>>4)*4 + v]

    // ---- MFMA layout probes (decode true D row/col lane-maps at runtime) ----
    int pl = tid & 63;
    int pli = pl & 15, plk = pl >> 4;
    int cof;
    {
        f64x4 pr = {0.0, 0.0, 0.0, 0.0}, pc = {0.0, 0.0, 0.0, 0.0};
        // probe R: A[:,k0] = row-id+1, B = e00  =>  D[i][j0] = i+1, else 0
        pr = __builtin_amdgcn_mfma_f64_16x16x4f64((plk == 0) ? (double)(pli + 1) : 0.0,
                                                  (plk == 0 && pli == 0) ? 1.0 : 0.0,
                                                  pr, 0, 0, 0);
        // probe C: A[:,k0] = 1, B[k0,:] = col-id+1  =>  D[i][j] = col(j)+1
        pc = __builtin_amdgcn_mfma_f64_16x16x4f64((plk == 0) ? 1.0 : 0.0,
                                                  (plk == 0) ? (double)(pli + 1) : 0.0,
                                                  pc, 0, 0, 0);
        cof = (int)pc[0] - 1;          // this lane's true output-column offset (0..15)
        if (cof == 0) {                // this lane reads column j0: pr[v] = true-row+1
            #pragma unroll
            for (int v = 0; v < 4; ++v) rowtab[plk * 4 + v] = (int)pr[v] - 1;
        }
        // fence before use: first GJ __syncthreads below
    }

    // ---- phase 1: register GJ on the 64x64 diag block ----
    int i = tid >> 3, g = tid & 7, c0 = g << 3;   // row i, col group g (8 cols)
    double c[8];
    {
        const double* src = M + (size_t)(kb * 64 + i) * S + kb * 64 + c0;
        #pragma unroll
        for (int m2 = 0; m2 < 4; ++m2) {
            double2 t = *(const double2*)(src + 2 * m2);
            c[2 * m2] = t.x; c[2 * m2 + 1] = t.y;
        }
    }
    double* rbuf = SCR;          // [2][64]
    double* cbuf = SCR + 128;    // [2][64]
    if (i == 0) {
        #pragma unroll
        for (int u = 0; u < 8; ++u) rbuf[c0 + u] = c[u];
    }
    if (g == 0) cbuf[i] = c[0];
    for (int k = 0; k < 64; ++k) {
        int par = k & 1;
        __syncthreads();
        double pv = rbuf[par * 64 + k];
        double f  = cbuf[par * 64 + i];
        double rk[8];
        #pragma unroll
        for (int m2 = 0; m2 < 4; ++m2) {
            double2 t = *(const double2*)&rbuf[par * 64 + c0 + 2 * m2];
            rk[2 * m2] = t.x; rk[2 * m2 + 1] = t.y;
        }
        double pivinv = 1.0 / pv;
        int kg = k >> 3, ks = k & 7;
        if (i == k) {
            #pragma unroll
            for (int u = 0; u < 8; ++u)
                c[u] = ((g == kg) && (u == ks)) ? pivinv : c[u] * pivinv;
        } else {
            double gm = f * pivinv;
            #pragma unroll
            for (int u = 0; u < 8; ++u)
                c[u] = ((g == kg) && (u == ks)) ? (-gm) : fma(-gm, rk[u], c[u]);
        }
        int k1 = k + 1;
        if (k1 < 64) {
            if (i == k1) {
                #pragma unroll
                for (int u = 0; u < 8; ++u) rbuf[(par ^ 1) * 64 + c0 + u] = c[u];
            }
            if (g == (k1 >> 3)) cbuf[(par ^ 1) * 64 + i] = c[k1 & 7];
        }
    }
    // Pinv -> H pivot-col region (A-operand source for phase 2; also final H content)
    #pragma unroll
    for (int u = 0; u < 8; ++u) H[i * HS + kb * 64 + c0 + u] = c[u];
    __syncthreads();                     // Pinv visible; rowtab visible

    int r0 = rowtab[plk * 4 + 0], r1 = rowtab[plk * 4 + 1];
    int r2 = rowtab[plk * 4 + 2], r3 = rowtab[plk * 4 + 3];
    int wv = tid >> 6;
    int li = pli, lk = plk;

    // ---- phase 2 (MFMA): G = Pinv * R_old -> H non-pivot cols ----
    // 48 tiles (4 row-tiles x 12 col-tiles); wave wv takes tiles t = (grp*3+j)*8 + wv.
    for (int grp = 0; grp < 2; ++grp) {
        int t0 = (grp * 3 + 0) * 8 + wv, t1 = (grp * 3 + 1) * 8 + wv, t2 = (grp * 3 + 2) * 8 + wv;
        int rtA = t0 / 12, clA = t0 % 12;
        int rtB = t1 / 12, clB = t1 % 12;
        int rtC = t2 / 12, clC = t2 % 12;
        int rmA = rowmap(clA * 16, kb), rmB = rowmap(clB * 16, kb), rmC = rowmap(clC * 16, kb);
        f64x4 aA = {0.0, 0.0, 0.0, 0.0};
        f64x4 aB = {0.0, 0.0, 0.0, 0.0};
        f64x4 aC = {0.0, 0.0, 0.0, 0.0};
        #pragma unroll
        for (int s = 0; s < 16; ++s) {
            int kk = 4 * s + lk;
            const double* Rrow = M + (size_t)(kb * 64 + kk) * S;
            double pA = H[(rtA * 16 + li) * HS + kb * 64 + kk];
            double pB = H[(rtB * 16 + li) * HS + kb * 64 + kk];
            double pC = H[(rtC * 16 + li) * HS + kb * 64 + kk];
            aA = __builtin_amdgcn_mfma_f64_16x16x4f64(pA, Rrow[rmA + li], aA, 0, 0, 0);
            aB = __builtin_amdgcn_mfma_f64_16x16x4f64(pB, Rrow[rmB + li], aB, 0, 0, 0);
            aC = __builtin_amdgcn_mfma_f64_16x16x4f64(pC, Rrow[rmC + li], aC, 0, 0, 0);
        }
        H[(rtA * 16 + r0) * HS + rmA + cof] = aA[0];
        H[(rtA * 16 + r1) * HS + rmA + cof] = aA[1];
        H[(rtA * 16 + r2) * HS + rmA + cof] = aA[2];
        H[(rtA * 16 + r3) * HS + rmA + cof] = aA[3];
        H[(rtB * 16 + r0) * HS + rmB + cof] = aB[0];
        H[(rtB * 16 + r1) * HS + rmB + cof] = aB[1];
        H[(rtB * 16 + r2) * HS + rmB + cof] = aB[2];
        H[(rtB * 16 + r3) * HS + rmB + cof] = aB[3];
        H[(rtC * 16 + r0) * HS + rmC + cof] = aC[0];
        H[(rtC * 16 + r1) * HS + rmC + cof] = aC[1];
        H[(rtC * 16 + r2) * HS + rmC + cof] = aC[2];
        H[(rtC * 16 + r3) * HS + rmC + cof] = aC[3];
    }
    __syncthreads();                     // H complete (G + Pinv); all R-reads done

    // H -> M pivot rows (global writes drain under the update phase)
    #pragma unroll
    for (int rep = 0; rep < 16; ++rep) {
        int idx = rep * 512 + tid;
        int row = idx >> 7, col2 = idx & 127;
        *(double2*)&M[(size_t)(kb * 64 + row) * S + 2 * col2] =
            *(const double2*)&H[row * HS + 2 * col2];
    }

    // ---- phase 3 (probe-calibrated MFMA): M[np rows] += (-F)*H ; pivot cols = (-F)*Pinv ----
    {
        int ct0 = 2 * wv, ct1 = 2 * wv + 1;          // this wave's two col-tiles
        bool pivw = ((wv >> 1) == kb);               // wave owns the pivot col-tiles
        for (int rt = 0; rt < 12; ++rt) {
            const double* Fp = M + (size_t)rowmap(rt * 16 + li, kb) * S + kb * 64 + lk;
            f64x4 acc0 = {0.0, 0.0, 0.0, 0.0};
            f64x4 acc1 = {0.0, 0.0, 0.0, 0.0};
            #pragma unroll
            for (int s = 0; s < 16; ++s) {
                double a  = -Fp[4 * s];                            // A = -F (global, L2-hot)
                double b0 = H[(4 * s + lk) * HS + 16 * ct0 + li];  // B = H (LDS)
                double b1 = H[(4 * s + lk) * HS + 16 * ct1 + li];
                acc0 = __builtin_amdgcn_mfma_f64_16x16x4f64(a, b0, acc0, 0, 0, 0);
                acc1 = __builtin_amdgcn_mfma_f64_16x16x4f64(a, b1, acc1, 0, 0, 0);
            }
            size_t g0 = (size_t)rowmap(rt * 16 + r0, kb) * S;
            size_t g1 = (size_t)rowmap(rt * 16 + r1, kb) * S;
            size_t g2 = (size_t)rowmap(rt * 16 + r2, kb) * S;
            size_t g3 = (size_t)rowmap(rt * 16 + r3, kb) * S;
            if (!pivw) {                              // non-pivot cols: RMW (no F alias)
                M[g0 + 16 * ct0 + cof] += acc0[0]; M[g0 + 16 * ct1 + cof] += acc1[0];
                M[g1 + 16 * ct0 + cof] += acc0[1]; M[g1 + 16 * ct1 + cof] += acc1[1];
                M[g2 + 16 * ct0 + cof] += acc0[2]; M[g2 + 16 * ct1 + cof] += acc1[2];
                M[g3 + 16 * ct0 + cof] += acc0[3]; M[g3 + 16 * ct1 + cof] += acc1[3];
            }
            __syncthreads();                          // all F-reads of this rt complete
            if (pivw) {                               // pivot cols overwrite F: after barrier
                M[g0 + 16 * ct0 + cof] = acc0[0]; M[g0 + 16 * ct1 + cof] = acc1[0];
                M[g1 + 16 * ct0 + cof] = acc0[1]; M[g1 + 16 * ct1 + cof] = acc1[1];
                M[g2 + 16 * ct0 + cof] = acc0[2]; M[g2 + 16 * ct1 + cof] = acc1[2];
                M[g3 + 16 * ct0 + cof] = acc0[3]; M[g3 + 16 * ct1 + cof] = acc1[3];
            }
        }
    }
}

// ---------------- kernel 4a: diag extract + row-0/col-0 epilogue ----------------------------
__global__ __launch_bounds__(256) void k_diag(const double* __restrict__ Mg,
                                              const float* __restrict__ sc,
                                              const double* __restrict__ mb,
                                              const int* __restrict__ nb,
                                              double* __restrict__ Dg,
                                              float* __restrict__ out) {
    int b = blockIdx.x, t = threadIdx.x;
    const double* M = Mg + (size_t)b * S * S;
    __shared__ double sd[256];
    double d = M[(size_t)t * S + t];
    sd[t] = d;
    Dg[(size_t)b * S + t] = d;
    out[(size_t)b * S * S + t] = 0.0f;            // row 0
    __syncthreads();
    int n = nb[b];
    float m = (float)mb[b];
    if (t >= 1) {                                 // col 0, rows 1..255
        float v = 0.0f;
        if (t <= n) {
            double A = (double)expf(sc[((size_t)b * S + t) * S + 0] - m);
            v = (float)(A * sd[t - 1]);
        }
        out[((size_t)b * S + t) * S + 0] = v;
    }
}

// ---------------- kernel 4b: fused transpose + epilogue (i,j >= 1) --------------------------
__global__ __launch_bounds__(256) void k_xtepi(const double* __restrict__ Mg,
                                               const float* __restrict__ sc,
                                               const double* __restrict__ mb,
                                               const int* __restrict__ nb,
                                               const double* __restrict__ Dg,
                                               float* __restrict__ out) {
    int b = blockIdx.y, t = blockIdx.x;
    int r = t & 3, c = t >> 2;
    const double* M = Mg + (size_t)b * S * S;
    __shared__ float L[64][65];
    __shared__ double sdg[64];
    int tid = threadIdx.x;
    int cc = tid & 63;
    #pragma unroll
    for (int rep = 0; rep < 16; ++rep) {
        int rr = rep * 4 + (tid >> 6);
        L[rr][cc] = (float)M[(size_t)(64 * r + rr) * S + 64 * c + cc];
    }
    if (tid < 64) sdg[tid] = Dg[(size_t)b * S + 64 * c + tid];
    __syncthreads();
    int n = nb[b];
    float m = (float)mb[b];
    int pp = tid & 63;
    #pragma unroll
    for (int rep = 0; rep < 16; ++rep) {
        int qq = rep * 4 + (tid >> 6);
        int orow = 64 * c + qq + 1, ocol = 64 * r + pp + 1;
        if (orow < 256 && ocol < 256) {
            float v = 0.0f;
            if (orow <= n && ocol <= n) {
                double A = (double)expf(sc[((size_t)b * S + orow) * S + ocol] - m);
                v = (float)(A * (sdg[qq] - (double)L[pp][qq]));
            }
            out[((size_t)b * S + orow) * S + ocol] = v;
        }
    }
}

// ---------------- launcher ----------------
extern "C" void kernel_launch(void* const* d_in, const int* in_sizes, int n_in,
                              void* d_out, int out_size, void* d_ws, size_t ws_size,
                              hipStream_t stream) {
    (void)in_sizes; (void)n_in; (void)out_size; (void)ws_size;
    const float* sc = (const float*)d_in[0];
    const unsigned char* mk = (const unsigned char*)d_in[1];
    double* ws = (double*)d_ws;

    double* M  = ws;                                 // B*256*256
    double* mb = M + (size_t)BB * S * S;             // B doubles
    int*    nb = (int*)(mb + BB);                    // B ints
    double* Dg = mb + 2 * BB;                        // B*256 doubles
    float*  partial = (float*)Dg;                    // aliases Dg (consumed before Dg written)
    float*  out = (float*)d_out;

    k_max<<<dim3(8, BB), 256, 0, stream>>>(sc, partial);
    k_n<<<BB, 256, 0, stream>>>(mk, partial, mb, nb);
    k_build<<<dim3(64, BB), 256, 0, stream>>>(sc, mb, nb, M);
    for (int kb = 0; kb < 4; ++kb)
        k_step<<<BB, 512, 0, stream>>>(M, kb);
    k_diag<<<BB, 256, 0, stream>>>(M, sc, mb, nb, Dg, out);
    k_xtepi<<<dim3(16, BB), 256, 0, stream>>>(M, sc, mb, nb, Dg, out);
}

// Round 17
// 532.287 us; speedup vs baseline: 1.0888x; 1.0389x over previous
//
#include <hip/hip_runtime.h>
#include <math.h>

// Matrix-Tree marginals: probs[b,i,j] = A[i,j]*(X[i-1,i-1] - (j>=1 ? X[j-1,i-1] : 0))
// X = inv(M) via blocked in-place Gauss-Jordan (4 panel steps of 64, SDD -> no pivoting).
// Round-17: R16 (MFMA phases 2+3, probe-calibrated) + phase-3 BARRIER ELIMINATION.
// R16's 12 per-rt barriers existed only because pivot waves overwrite the F panel others
// read. Now pivot-col results go to a global side buffer Pg (aliases d_out, rewritten by
// k_diag/k_xtepi); phase-3 loop has no cross-wave aliasing -> no barriers, F-loads pipeline
// across rt iterations; ONE barrier + coalesced Pg->M copy at the end.
// ws (doubles): M[B][256][256] | mb[B] | nb[B](int) | Dg[B][256]; partial aliases Dg.

#define S 256
#define BB 256
#define HS 258

typedef double f64x4 __attribute__((ext_vector_type(4)));

__device__ __forceinline__ int rowmap(int lr, int kb) {   // local 0..191 -> global row skipping panel kb
    int rt = lr >> 6;
    int rb = rt + (rt >= kb ? 1 : 0);
    return rb * 64 + (lr & 63);
}

// ---------------- kernel 1a: dense max over each batch's full 256x256 score matrix ----------
__global__ __launch_bounds__(256) void k_max(const float* __restrict__ sc,
                                             float* __restrict__ partial) {
    int b = blockIdx.y, rg = blockIdx.x;                 // 8 row-groups of 32 rows
    const float4* p4 = (const float4*)(sc + (size_t)b * S * S + rg * 8192);
    int tid = threadIdx.x;
    float4 v[8];
    #pragma unroll
    for (int it = 0; it < 8; ++it) v[it] = p4[tid + 256 * it];
    float m = -1e30f;
    #pragma unroll
    for (int it = 0; it < 8; ++it)
        m = fmaxf(m, fmaxf(fmaxf(v[it].x, v[it].y), fmaxf(v[it].z, v[it].w)));
    for (int off = 32; off > 0; off >>= 1) m = fmaxf(m, __shfl_down(m, off));
    __shared__ float sm[4];
    if ((tid & 63) == 0) sm[tid >> 6] = m;
    __syncthreads();
    if (tid == 0) partial[b * 8 + rg] = fmaxf(fmaxf(sm[0], sm[1]), fmaxf(sm[2], sm[3]));
}

// ---------------- kernel 1b: per-batch n (mask count) + combine partial maxima --------------
__global__ void k_n(const unsigned char* __restrict__ mk, const float* __restrict__ partial,
                    double* __restrict__ mb, int* __restrict__ nb) {
    int b = blockIdx.x, j = threadIdx.x;
    __shared__ int shc[4];

    const unsigned int* mw = (const unsigned int*)mk;    // sniff mask dtype
    unsigned int w0 = mw[0], w1 = mw[1];
    int mode = (w0 != 0u) ? 0 : ((w1 != 0u) ? 1 : 2);

    int c;
    if (mode == 0)      c = (mk[(size_t)b * S + j] != 0);
    else if (mode == 1) c = (((const int*)mk)[(size_t)b * S + j] != 0);
    else                c = (((const long long*)mk)[(size_t)b * S + j] != 0LL);

    int lane = j & 63, wid = j >> 6;
    int cs = c;
    for (int off = 32; off > 0; off >>= 1) cs += __shfl_down(cs, off);
    if (lane == 0) shc[wid] = cs;
    __syncthreads();
    if (j == 0) {
        nb[b] = shc[0] + shc[1] + shc[2] + shc[3];
        float mm = partial[b * 8];
        #pragma unroll
        for (int q = 1; q < 8; ++q) mm = fmaxf(mm, partial[b * 8 + q]);
        mb[b] = (double)mm;
    }
}

// ---------------- kernel 2: build padded M (f64, expf), 4 rows per block --------------------
__global__ __launch_bounds__(256) void k_build(const float* __restrict__ sc,
                                               const double* __restrict__ mb,
                                               const int* __restrict__ nb,
                                               double* __restrict__ Mg) {
    int b = blockIdx.y;
    int wid = threadIdx.x >> 6, lane = threadIdx.x & 63;
    int p = blockIdx.x * 4 + wid;
    int n = nb[b];
    double m = mb[b];
    __shared__ double se[4][260];
    double* Mrow = Mg + ((size_t)b * S + p) * S;
    bool act = (p < n);
    double ssum = 0.0;
    #pragma unroll
    for (int c4 = 0; c4 < 4; ++c4) {
        int j = lane + 64 * c4;
        double ev = 0.0;
        if (act && j <= n)
            ev = (double)expf((float)((double)sc[((size_t)b * S + (p + 1)) * S + j] - m));
        se[wid][j] = ev;
        ssum += ev;
    }
    for (int off = 32; off > 0; off >>= 1) ssum += __shfl_down(ssum, off);
    ssum = __shfl(ssum, 0);
    __syncthreads();                       // uniform: all 4 waves reach it
    #pragma unroll
    for (int c4 = 0; c4 < 4; ++c4) {
        int j = lane + 64 * c4;
        double v;
        if (act && j < n) v = ((j == p) ? ssum : 0.0) - se[wid][j + 1];
        else              v = (j == p) ? 1.0 : 0.0;
        Mrow[j] = v;
    }
}

// ---------------- kernel 3: fused panel step (GJ + MFMA rowG + barrier-free MFMA update) ----
__global__ __launch_bounds__(512) void k_step(double* __restrict__ Mg,
                                              double* __restrict__ Pg, int kb) {
    int b = blockIdx.x;
    double* M = Mg + (size_t)b * S * S;
    double* Pgb = Pg + (size_t)b * (192 * 64);   // pivot-col side buffer (192 np-rows x 64)
    int tid = threadIdx.x;
    __shared__ double H[64 * HS];      // [G | Pinv] by GLOBAL column index, rows = pivot rows
    __shared__ double SCR[256];        // GJ row/col broadcast buffers
    __shared__ int rowtab[16];         // decoded D-row map: rowtab[(lane>>4)*4 + v]

    // ---- MFMA layout probes (decode true D row/col lane-maps at runtime) ----
    int pl = tid & 63;
    int pli = pl & 15, plk = pl >> 4;
    int cof;
    {
        f64x4 pr = {0.0, 0.0, 0.0, 0.0}, pc = {0.0, 0.0, 0.0, 0.0};
        // probe R: A[:,k0] = row-id+1, B = e00  =>  D[i][j0] = i+1, else 0
        pr = __builtin_amdgcn_mfma_f64_16x16x4f64((plk == 0) ? (double)(pli + 1) : 0.0,
                                                  (plk == 0 && pli == 0) ? 1.0 : 0.0,
                                                  pr, 0, 0, 0);
        // probe C: A[:,k0] = 1, B[k0,:] = col-id+1  =>  D[i][j] = col(j)+1
        pc = __builtin_amdgcn_mfma_f64_16x16x4f64((plk == 0) ? 1.0 : 0.0,
                                                  (plk == 0) ? (double)(pli + 1) : 0.0,
                                                  pc, 0, 0, 0);
        cof = (int)pc[0] - 1;          // this lane's true output-column offset (0..15)
        if (cof == 0) {                // this lane reads column j0: pr[v] = true-row+1
            #pragma unroll
            for (int v = 0; v < 4; ++v) rowtab[plk * 4 + v] = (int)pr[v] - 1;
        }
        // fence before use: first GJ __syncthreads below
    }

    // ---- phase 1: register GJ on the 64x64 diag block ----
    int i = tid >> 3, g = tid & 7, c0 = g << 3;   // row i, col group g (8 cols)
    double c[8];
    {
        const double* src = M + (size_t)(kb * 64 + i) * S + kb * 64 + c0;
        #pragma unroll
        for (int m2 = 0; m2 < 4; ++m2) {
            double2 t = *(const double2*)(src + 2 * m2);
            c[2 * m2] = t.x; c[2 * m2 + 1] = t.y;
        }
    }
    double* rbuf = SCR;          // [2][64]
    double* cbuf = SCR + 128;    // [2][64]
    if (i == 0) {
        #pragma unroll
        for (int u = 0; u < 8; ++u) rbuf[c0 + u] = c[u];
    }
    if (g == 0) cbuf[i] = c[0];
    for (int k = 0; k < 64; ++k) {
        int par = k & 1;
        __syncthreads();
        double pv = rbuf[par * 64 + k];
        double f  = cbuf[par * 64 + i];
        double rk[8];
        #pragma unroll
        for (int m2 = 0; m2 < 4; ++m2) {
            double2 t = *(const double2*)&rbuf[par * 64 + c0 + 2 * m2];
            rk[2 * m2] = t.x; rk[2 * m2 + 1] = t.y;
        }
        double pivinv = 1.0 / pv;
        int kg = k >> 3, ks = k & 7;
        if (i == k) {
            #pragma unroll
            for (int u = 0; u < 8; ++u)
                c[u] = ((g == kg) && (u == ks)) ? pivinv : c[u] * pivinv;
        } else {
            double gm = f * pivinv;
            #pragma unroll
            for (int u = 0; u < 8; ++u)
                c[u] = ((g == kg) && (u == ks)) ? (-gm) : fma(-gm, rk[u], c[u]);
        }
        int k1 = k + 1;
        if (k1 < 64) {
            if (i == k1) {
                #pragma unroll
                for (int u = 0; u < 8; ++u) rbuf[(par ^ 1) * 64 + c0 + u] = c[u];
            }
            if (g == (k1 >> 3)) cbuf[(par ^ 1) * 64 + i] = c[k1 & 7];
        }
    }
    // Pinv -> H pivot-col region (A-operand source for phase 2; also final H content)
    #pragma unroll
    for (int u = 0; u < 8; ++u) H[i * HS + kb * 64 + c0 + u] = c[u];
    __syncthreads();                     // Pinv visible; rowtab visible

    int r0 = rowtab[plk * 4 + 0], r1 = rowtab[plk * 4 + 1];
    int r2 = rowtab[plk * 4 + 2], r3 = rowtab[plk * 4 + 3];
    int wv = tid >> 6;
    int li = pli, lk = plk;

    // ---- phase 2 (MFMA): G = Pinv * R_old -> H non-pivot cols ----
    // 48 tiles (4 row-tiles x 12 col-tiles); wave wv takes tiles t = (grp*3+j)*8 + wv.
    for (int grp = 0; grp < 2; ++grp) {
        int t0 = (grp * 3 + 0) * 8 + wv, t1 = (grp * 3 + 1) * 8 + wv, t2 = (grp * 3 + 2) * 8 + wv;
        int rtA = t0 / 12, clA = t0 % 12;
        int rtB = t1 / 12, clB = t1 % 12;
        int rtC = t2 / 12, clC = t2 % 12;
        int rmA = rowmap(clA * 16, kb), rmB = rowmap(clB * 16, kb), rmC = rowmap(clC * 16, kb);
        f64x4 aA = {0.0, 0.0, 0.0, 0.0};
        f64x4 aB = {0.0, 0.0, 0.0, 0.0};
        f64x4 aC = {0.0, 0.0, 0.0, 0.0};
        #pragma unroll
        for (int s = 0; s < 16; ++s) {
            int kk = 4 * s + lk;
            const double* Rrow = M + (size_t)(kb * 64 + kk) * S;
            double pA = H[(rtA * 16 + li) * HS + kb * 64 + kk];
            double pB = H[(rtB * 16 + li) * HS + kb * 64 + kk];
            double pC = H[(rtC * 16 + li) * HS + kb * 64 + kk];
            aA = __builtin_amdgcn_mfma_f64_16x16x4f64(pA, Rrow[rmA + li], aA, 0, 0, 0);
            aB = __builtin_amdgcn_mfma_f64_16x16x4f64(pB, Rrow[rmB + li], aB, 0, 0, 0);
            aC = __builtin_amdgcn_mfma_f64_16x16x4f64(pC, Rrow[rmC + li], aC, 0, 0, 0);
        }
        H[(rtA * 16 + r0) * HS + rmA + cof] = aA[0];
        H[(rtA * 16 + r1) * HS + rmA + cof] = aA[1];
        H[(rtA * 16 + r2) * HS + rmA + cof] = aA[2];
        H[(rtA * 16 + r3) * HS + rmA + cof] = aA[3];
        H[(rtB * 16 + r0) * HS + rmB + cof] = aB[0];
        H[(rtB * 16 + r1) * HS + rmB + cof] = aB[1];
        H[(rtB * 16 + r2) * HS + rmB + cof] = aB[2];
        H[(rtB * 16 + r3) * HS + rmB + cof] = aB[3];
        H[(rtC * 16 + r0) * HS + rmC + cof] = aC[0];
        H[(rtC * 16 + r1) * HS + rmC + cof] = aC[1];
        H[(rtC * 16 + r2) * HS + rmC + cof] = aC[2];
        H[(rtC * 16 + r3) * HS + rmC + cof] = aC[3];
    }
    __syncthreads();                     // H complete (G + Pinv); all R-reads done

    // H -> M pivot rows (global writes drain under the update phase)
    #pragma unroll
    for (int rep = 0; rep < 16; ++rep) {
        int idx = rep * 512 + tid;
        int row = idx >> 7, col2 = idx & 127;
        *(double2*)&M[(size_t)(kb * 64 + row) * S + 2 * col2] =
            *(const double2*)&H[row * HS + 2 * col2];
    }

    // ---- phase 3 (barrier-free MFMA): M[np rows] += (-F)*H ; pivot cols -> Pg -------------
    // No cross-wave aliasing: non-pivot RMW cols, F-read cols (pivot panel), and Pg are
    // pairwise disjoint, so no intra-loop barriers; F-loads pipeline across rt.
    {
        int ct0 = 2 * wv, ct1 = 2 * wv + 1;          // this wave's two col-tiles
        bool pivw = ((wv >> 1) == kb);               // wave owns the pivot col-tiles
        int lc0 = 16 * ct0 + cof - 64 * kb;          // pivot-local cols (0..63) when pivw
        int lc1 = lc0 + 16;
        #pragma unroll 1
        for (int rt = 0; rt < 12; ++rt) {
            const double* Fp = M + (size_t)rowmap(rt * 16 + li, kb) * S + kb * 64 + lk;
            f64x4 acc0 = {0.0, 0.0, 0.0, 0.0};
            f64x4 acc1 = {0.0, 0.0, 0.0, 0.0};
            #pragma unroll
            for (int s = 0; s < 16; ++s) {
                double a  = -Fp[4 * s];                            // A = -F (global, L2-hot)
                double b0 = H[(4 * s + lk) * HS + 16 * ct0 + li];  // B = H (LDS)
                double b1 = H[(4 * s + lk) * HS + 16 * ct1 + li];
                acc0 = __builtin_amdgcn_mfma_f64_16x16x4f64(a, b0, acc0, 0, 0, 0);
                acc1 = __builtin_amdgcn_mfma_f64_16x16x4f64(a, b1, acc1, 0, 0, 0);
            }
            if (!pivw) {                              // non-pivot cols: RMW (disjoint from F)
                size_t g0 = (size_t)rowmap(rt * 16 + r0, kb) * S;
                size_t g1 = (size_t)rowmap(rt * 16 + r1, kb) * S;
                size_t g2 = (size_t)rowmap(rt * 16 + r2, kb) * S;
                size_t g3 = (size_t)rowmap(rt * 16 + r3, kb) * S;
                M[g0 + 16 * ct0 + cof] += acc0[0]; M[g0 + 16 * ct1 + cof] += acc1[0];
                M[g1 + 16 * ct0 + cof] += acc0[1]; M[g1 + 16 * ct1 + cof] += acc1[1];
                M[g2 + 16 * ct0 + cof] += acc0[2]; M[g2 + 16 * ct1 + cof] += acc1[2];
                M[g3 + 16 * ct0 + cof] += acc0[3]; M[g3 + 16 * ct1 + cof] += acc1[3];
            } else {                                  // pivot cols: side buffer, no hazard
                Pgb[(rt * 16 + r0) * 64 + lc0] = acc0[0]; Pgb[(rt * 16 + r0) * 64 + lc1] = acc1[0];
                Pgb[(rt * 16 + r1) * 64 + lc0] = acc0[1]; Pgb[(rt * 16 + r1) * 64 + lc1] = acc1[1];
                Pgb[(rt * 16 + r2) * 64 + lc0] = acc0[2]; Pgb[(rt * 16 + r2) * 64 + lc1] = acc1[2];
                Pgb[(rt * 16 + r3) * 64 + lc0] = acc0[3]; Pgb[(rt * 16 + r3) * 64 + lc1] = acc1[3];
            }
        }
    }
    __syncthreads();                     // all F reads done + Pg writes visible
    // Pg -> M pivot cols (coalesced)
    #pragma unroll
    for (int rep = 0; rep < 12; ++rep) {
        int idx = rep * 512 + tid;       // 0..6143 double2
        int lr = idx >> 5, cp = idx & 31;
        *(double2*)&M[(size_t)rowmap(lr, kb) * S + kb * 64 + 2 * cp] =
            *(const double2*)&Pgb[lr * 64 + 2 * cp];
    }
}

// ---------------- kernel 4a: diag extract + row-0/col-0 epilogue ----------------------------
__global__ __launch_bounds__(256) void k_diag(const double* __restrict__ Mg,
                                              const float* __restrict__ sc,
                                              const double* __restrict__ mb,
                                              const int* __restrict__ nb,
                                              double* __restrict__ Dg,
                                              float* __restrict__ out) {
    int b = blockIdx.x, t = threadIdx.x;
    const double* M = Mg + (size_t)b * S * S;
    __shared__ double sd[256];
    double d = M[(size_t)t * S + t];
    sd[t] = d;
    Dg[(size_t)b * S + t] = d;
    out[(size_t)b * S * S + t] = 0.0f;            // row 0
    __syncthreads();
    int n = nb[b];
    float m = (float)mb[b];
    if (t >= 1) {                                 // col 0, rows 1..255
        float v = 0.0f;
        if (t <= n) {
            double A = (double)expf(sc[((size_t)b * S + t) * S + 0] - m);
            v = (float)(A * sd[t - 1]);
        }
        out[((size_t)b * S + t) * S + 0] = v;
    }
}

// ---------------- kernel 4b: fused transpose + epilogue (i,j >= 1) --------------------------
__global__ __launch_bounds__(256) void k_xtepi(const double* __restrict__ Mg,
                                               const float* __restrict__ sc,
                                               const double* __restrict__ mb,
                                               const int* __restrict__ nb,
                                               const double* __restrict__ Dg,
                                               float* __restrict__ out) {
    int b = blockIdx.y, t = blockIdx.x;
    int r = t & 3, c = t >> 2;
    const double* M = Mg + (size_t)b * S * S;
    __shared__ float L[64][65];
    __shared__ double sdg[64];
    int tid = threadIdx.x;
    int cc = tid & 63;
    #pragma unroll
    for (int rep = 0; rep < 16; ++rep) {
        int rr = rep * 4 + (tid >> 6);
        L[rr][cc] = (float)M[(size_t)(64 * r + rr) * S + 64 * c + cc];
    }
    if (tid < 64) sdg[tid] = Dg[(size_t)b * S + 64 * c + tid];
    __syncthreads();
    int n = nb[b];
    float m = (float)mb[b];
    int pp = tid & 63;
    #pragma unroll
    for (int rep = 0; rep < 16; ++rep) {
        int qq = rep * 4 + (tid >> 6);
        int orow = 64 * c + qq + 1, ocol = 64 * r + pp + 1;
        if (orow < 256 && ocol < 256) {
            float v = 0.0f;
            if (orow <= n && ocol <= n) {
                double A = (double)expf(sc[((size_t)b * S + orow) * S + ocol] - m);
                v = (float)(A * (sdg[qq] - (double)L[pp][qq]));
            }
            out[((size_t)b * S + orow) * S + ocol] = v;
        }
    }
}

// ---------------- launcher ----------------
extern "C" void kernel_launch(void* const* d_in, const int* in_sizes, int n_in,
                              void* d_out, int out_size, void* d_ws, size_t ws_size,
                              hipStream_t stream) {
    (void)in_sizes; (void)n_in; (void)out_size; (void)ws_size;
    const float* sc = (const float*)d_in[0];
    const unsigned char* mk = (const unsigned char*)d_in[1];
    double* ws = (double*)d_ws;

    double* M  = ws;                                 // B*256*256
    double* mb = M + (size_t)BB * S * S;             // B doubles
    int*    nb = (int*)(mb + BB);                    // B ints
    double* Dg = mb + 2 * BB;                        // B*256 doubles
    float*  partial = (float*)Dg;                    // aliases Dg (consumed before Dg written)
    float*  out = (float*)d_out;
    double* Pg = (double*)d_out;                     // 25MB pivot-col side buffer (rewritten
                                                     // in full by k_diag/k_xtepi afterwards)

    k_max<<<dim3(8, BB), 256, 0, stream>>>(sc, partial);
    k_n<<<BB, 256, 0, stream>>>(mk, partial, mb, nb);
    k_build<<<dim3(64, BB), 256, 0, stream>>>(sc, mb, nb, M);
    for (int kb = 0; kb < 4; ++kb)
        k_step<<<BB, 512, 0, stream>>>(M, Pg, kb);
    k_diag<<<BB, 256, 0, stream>>>(M, sc, mb, nb, Dg, out);
    k_xtepi<<<dim3(16, BB), 256, 0, stream>>>(M, sc, mb, nb, Dg, out);
}